// Round 24
// baseline (244.502 us; speedup 1.0000x reference)
//
#include <hip/hip_runtime.h>
#include <math.h>

#define NB 16
#define NCH 128
#define NH 64
#define NW 64
#define NP 1024

#define TN 32
#define TM 128
#define KC 32
#define KP 36    // fp32 fallback pad
#define PK 42    // bf16 staging pad (ushorts): 84B rows -> odd-word stride, 2-way-free frag reads

#define NTILE 144  // symmetric tile count

typedef __attribute__((ext_vector_type(8))) short short8v;
typedef __attribute__((ext_vector_type(4))) float f32x4;

__device__ __forceinline__ float med3(float a, float b, float c) {
  return __builtin_amdgcn_fmed3f(a, b, c);
}
__device__ __forceinline__ void top3_ins(float& t0, float& t1, float& t2, float a) {
  float n0 = fmaxf(t0, a);
  float n1 = med3(a, t0, t1);
  float n2 = med3(a, t1, t2);
  t0 = n0; t1 = n1; t2 = n2;
}
__device__ __forceinline__ float dot4(float4 a, float4 b) {
  return a.x * b.x + a.y * b.y + a.z * b.z + a.w * b.w;
}
__device__ __forceinline__ ushort f2bf(float f) {  // RNE bf16
  unsigned u = __float_as_uint(f);
  unsigned r = (u + 0x7FFFu + ((u >> 16) & 1u)) >> 16;
  return (ushort)r;
}
__device__ __forceinline__ float bf2f(ushort h) {
  return __uint_as_float(((unsigned)h) << 16);
}
__device__ __forceinline__ int tile_base(int g) {  // sum_{h<g} 4*(8-h)
  return 32 * g - 2 * g * (g - 1);
}

// ---------------- prep_split (R16-verified) ----------------
__global__ __launch_bounds__(256) void prep_split(const float* __restrict__ x,
                                                  ushort* __restrict__ Vs,
                                                  float* __restrict__ rsum) {
  int blk = blockIdx.x;
  int t = threadIdx.x;
  int gid = blk * 256 + t;
  if (gid < NB * 3 * NP) rsum[gid] = 0.f;

  int b = blk >> 5;
  int c = (blk >> 4) & 1;
  int ng = blk & 15;
  int nl = t >> 2;
  int kq = t & 3;
  int n = ng * 64 + nl;
  int i = 2 * (n >> 5) + c;
  int j = 2 * (n & 31) + c;
  const float* xp = x + (size_t)b * NCH * NH * NW + i * NW + j;

  float v[32];
#pragma unroll
  for (int e = 0; e < 32; ++e)
    v[e] = xp[(size_t)(kq * 32 + e) * NH * NW];

  float ss = 0.f;
#pragma unroll
  for (int e = 0; e < 32; ++e) ss += v[e] * v[e];
  ss += __shfl_xor(ss, 1, 64);
  ss += __shfl_xor(ss, 2, 64);
  float r = 1.0f / fmaxf(sqrtf(ss), 1e-12f);

  size_t base = ((size_t)(b * 2 + c) * 3) * NP * NCH + (size_t)n * NCH + kq * 32;
  ushort* p1 = Vs + base;
  ushort* p2 = Vs + base + (size_t)NP * NCH;
  ushort* p3 = Vs + base + (size_t)2 * NP * NCH;
#pragma unroll
  for (int kg2 = 0; kg2 < 4; ++kg2) {
    ushort h1[8], h2[8], h3[8];
#pragma unroll
    for (int e = 0; e < 8; ++e) {
      float vv = v[kg2 * 8 + e] * r;
      ushort a = f2bf(vv);
      float r1 = vv - bf2f(a);
      ushort bq = f2bf(r1);
      float r2 = r1 - bf2f(bq);
      ushort cq = f2bf(r2);
      h1[e] = a; h2[e] = bq; h3[e] = cq;
    }
    *(float4*)(p1 + kg2 * 8) = *(float4*)h1;
    *(float4*)(p2 + kg2 * 8) = *(float4*)h2;
    *(float4*)(p3 + kg2 * 8) = *(float4*)h3;
  }
}

// ================= MFMA bf16x3 sym GEMM (R21/R22-verified): packed upper Sbuf + fused sums ====
__global__ __launch_bounds__(256, 4) void gemm_mfma(
    const ushort* __restrict__ Vs, const float* __restrict__ alpha_p,
    float2* __restrict__ Sbuf, float* __restrict__ rsum) {
  __shared__ __align__(16) char smem[3 * 32 * PK * 2 + 3 * 128 * PK * 2];  // 40320 B
  ushort (*A_s)[32][PK] = reinterpret_cast<ushort(*)[32][PK]>(smem);
  ushort (*B_s)[128][PK] =
      reinterpret_cast<ushort(*)[128][PK]>(smem + 3 * 32 * PK * 2);

  int wg = blockIdx.x;
  int xcd = wg & 7;
  int jj = wg >> 3;
  int half = (jj >= NTILE) ? 1 : 0;
  const int b = 2 * xcd + half;
  int id = jj - half * NTILE;
  const int tid0 = id;                     // packed tile index
  int g = 0;
  while (id >= 4 * (8 - g)) { id -= 4 * (8 - g); ++g; }
  const int ni = 4 * g + id / (8 - g);
  const int mj = g + id % (8 - g);
  const int n0 = ni * TN;
  const int m0 = mj * TM;

  const int t = threadIdx.x;
  const int lane = t & 63, wv = t >> 6;
  const int jc = lane & 15, kg = lane >> 4;
  const float alpha = *alpha_p;
  const ushort* Vsb = Vs + (size_t)b * 6 * NP * NCH;
  float* rs = rsum + (size_t)b * 3 * NP;

  f32x4 acc[2][2][2];
#pragma unroll
  for (int c = 0; c < 2; ++c)
#pragma unroll
    for (int i = 0; i < 2; ++i)
#pragma unroll
      for (int j = 0; j < 2; ++j) acc[c][i][j] = (f32x4){0.f, 0.f, 0.f, 0.f};

#pragma unroll
  for (int c = 0; c < 2; ++c) {
    for (int k0 = 0; k0 < NCH; k0 += KC) {
      __syncthreads();
#pragma unroll
      for (int q = 0; q < 2; ++q) {
        int flat = q * 256 + t;
        if (flat < 384) {
          int p = flat >> 7;
          int rem = flat & 127;
          int row = rem >> 2, u = rem & 3;
          const ushort* src = Vsb + ((size_t)(c * 3 + p) * NP + n0 + row) * NCH + k0 + u * 8;
          *(float4*)&A_s[p][row][u * 8] = *(const float4*)src;
        }
      }
#pragma unroll
      for (int q = 0; q < 6; ++q) {
        int flat = q * 256 + t;
        int p = flat >> 9;
        int rem = flat & 511;
        int row = rem >> 2, u = rem & 3;
        const ushort* src = Vsb + ((size_t)(c * 3 + p) * NP + m0 + row) * NCH + k0 + u * 8;
        *(float4*)&B_s[p][row][u * 8] = *(const float4*)src;
      }
      __syncthreads();

      short8v a1n0 = *(const short8v*)&A_s[0][jc][kg * 8];
      short8v a1n1 = *(const short8v*)&A_s[0][16 + jc][kg * 8];
      short8v a2n0 = *(const short8v*)&A_s[1][jc][kg * 8];
      short8v a2n1 = *(const short8v*)&A_s[1][16 + jc][kg * 8];
      short8v a3n0 = *(const short8v*)&A_s[2][jc][kg * 8];
      short8v a3n1 = *(const short8v*)&A_s[2][16 + jc][kg * 8];
      {
        short8v b0 = *(const short8v*)&B_s[0][wv * 32 + jc][kg * 8];
        short8v b1 = *(const short8v*)&B_s[0][wv * 32 + 16 + jc][kg * 8];
        acc[c][0][0] = __builtin_amdgcn_mfma_f32_16x16x32_bf16(a1n0, b0, acc[c][0][0], 0, 0, 0);
        acc[c][1][0] = __builtin_amdgcn_mfma_f32_16x16x32_bf16(a1n1, b0, acc[c][1][0], 0, 0, 0);
        acc[c][0][1] = __builtin_amdgcn_mfma_f32_16x16x32_bf16(a1n0, b1, acc[c][0][1], 0, 0, 0);
        acc[c][1][1] = __builtin_amdgcn_mfma_f32_16x16x32_bf16(a1n1, b1, acc[c][1][1], 0, 0, 0);
        acc[c][0][0] = __builtin_amdgcn_mfma_f32_16x16x32_bf16(a2n0, b0, acc[c][0][0], 0, 0, 0);
        acc[c][1][0] = __builtin_amdgcn_mfma_f32_16x16x32_bf16(a2n1, b0, acc[c][1][0], 0, 0, 0);
        acc[c][0][1] = __builtin_amdgcn_mfma_f32_16x16x32_bf16(a2n0, b1, acc[c][0][1], 0, 0, 0);
        acc[c][1][1] = __builtin_amdgcn_mfma_f32_16x16x32_bf16(a2n1, b1, acc[c][1][1], 0, 0, 0);
        acc[c][0][0] = __builtin_amdgcn_mfma_f32_16x16x32_bf16(a3n0, b0, acc[c][0][0], 0, 0, 0);
        acc[c][1][0] = __builtin_amdgcn_mfma_f32_16x16x32_bf16(a3n1, b0, acc[c][1][0], 0, 0, 0);
        acc[c][0][1] = __builtin_amdgcn_mfma_f32_16x16x32_bf16(a3n0, b1, acc[c][0][1], 0, 0, 0);
        acc[c][1][1] = __builtin_amdgcn_mfma_f32_16x16x32_bf16(a3n1, b1, acc[c][1][1], 0, 0, 0);
      }
      {
        short8v b0 = *(const short8v*)&B_s[1][wv * 32 + jc][kg * 8];
        short8v b1 = *(const short8v*)&B_s[1][wv * 32 + 16 + jc][kg * 8];
        acc[c][0][0] = __builtin_amdgcn_mfma_f32_16x16x32_bf16(a1n0, b0, acc[c][0][0], 0, 0, 0);
        acc[c][1][0] = __builtin_amdgcn_mfma_f32_16x16x32_bf16(a1n1, b0, acc[c][1][0], 0, 0, 0);
        acc[c][0][1] = __builtin_amdgcn_mfma_f32_16x16x32_bf16(a1n0, b1, acc[c][0][1], 0, 0, 0);
        acc[c][1][1] = __builtin_amdgcn_mfma_f32_16x16x32_bf16(a1n1, b1, acc[c][1][1], 0, 0, 0);
        acc[c][0][0] = __builtin_amdgcn_mfma_f32_16x16x32_bf16(a2n0, b0, acc[c][0][0], 0, 0, 0);
        acc[c][1][0] = __builtin_amdgcn_mfma_f32_16x16x32_bf16(a2n1, b0, acc[c][1][0], 0, 0, 0);
        acc[c][0][1] = __builtin_amdgcn_mfma_f32_16x16x32_bf16(a2n0, b1, acc[c][0][1], 0, 0, 0);
        acc[c][1][1] = __builtin_amdgcn_mfma_f32_16x16x32_bf16(a2n1, b1, acc[c][1][1], 0, 0, 0);
      }
      {
        short8v b0 = *(const short8v*)&B_s[2][wv * 32 + jc][kg * 8];
        short8v b1 = *(const short8v*)&B_s[2][wv * 32 + 16 + jc][kg * 8];
        acc[c][0][0] = __builtin_amdgcn_mfma_f32_16x16x32_bf16(a1n0, b0, acc[c][0][0], 0, 0, 0);
        acc[c][1][0] = __builtin_amdgcn_mfma_f32_16x16x32_bf16(a1n1, b0, acc[c][1][0], 0, 0, 0);
        acc[c][0][1] = __builtin_amdgcn_mfma_f32_16x16x32_bf16(a1n0, b1, acc[c][0][1], 0, 0, 0);
        acc[c][1][1] = __builtin_amdgcn_mfma_f32_16x16x32_bf16(a1n1, b1, acc[c][1][1], 0, 0, 0);
      }
    }
  }

  // ---- epilogue: tile write (m>=n) + row/col exp partials ----
  float e[2][4][3];
  float gcol[2][3];
#pragma unroll
  for (int ns = 0; ns < 2; ++ns)
#pragma unroll
    for (int r = 0; r < 4; ++r)
#pragma unroll
      for (int c = 0; c < 3; ++c) e[ns][r][c] = 0.f;
#pragma unroll
  for (int ms = 0; ms < 2; ++ms)
#pragma unroll
    for (int c = 0; c < 3; ++c) gcol[ms][c] = 0.f;

#pragma unroll
  for (int ns = 0; ns < 2; ++ns) {
#pragma unroll
    for (int r = 0; r < 4; ++r) {
      int nl = ns * 16 + kg * 4 + r;
      int n = n0 + nl;
      int nr = n >> 5, nc = n & 31;
      float2* rowp = Sbuf + ((size_t)(b * NTILE + tid0) * 32 + nl) * TM;
#pragma unroll
      for (int ms = 0; ms < 2; ++ms) {
        int ml = wv * 32 + ms * 16 + jc;
        int m = m0 + ml;
        int dr = nr - (m >> 5);
        int dc = nc - (m & 31);
        float gss = __expf(-(float)(dr * dr + dc * dc) * 0.1953125f);
        float wgt = (1.0f - gss) * alpha;
        float s0 = acc[0][ns][ms][r] * wgt;
        float s1 = acc[1][ns][ms][r] * wgt;
        float e0 = __expf(s0);
        float e1 = __expf(s1);
        float e2 = __expf(0.5f * (s0 + s1));
        if (m >= n) {
          rowp[ml] = make_float2(s0, s1);
          e[ns][r][0] += e0; e[ns][r][1] += e1; e[ns][r][2] += e2;
        }
        if (m > n) { gcol[ms][0] += e0; gcol[ms][1] += e1; gcol[ms][2] += e2; }
      }
    }
  }
#pragma unroll
  for (int off = 1; off < 16; off <<= 1) {
#pragma unroll
    for (int ns = 0; ns < 2; ++ns)
#pragma unroll
      for (int r = 0; r < 4; ++r)
#pragma unroll
        for (int c = 0; c < 3; ++c)
          e[ns][r][c] += __shfl_xor(e[ns][r][c], off, 64);
  }
  if (jc == 0) {
#pragma unroll
    for (int ns = 0; ns < 2; ++ns)
#pragma unroll
      for (int r = 0; r < 4; ++r)
#pragma unroll
        for (int c = 0; c < 3; ++c)
          atomicAdd(&rs[(size_t)c * NP + (n0 + ns * 16 + kg * 4 + r)], e[ns][r][c]);
  }
#pragma unroll
  for (int off = 16; off < 64; off <<= 1) {
#pragma unroll
    for (int ms = 0; ms < 2; ++ms)
#pragma unroll
      for (int c = 0; c < 3; ++c)
        gcol[ms][c] += __shfl_xor(gcol[ms][c], off, 64);
  }
  if (kg == 0) {
#pragma unroll
    for (int ms = 0; ms < 2; ++ms) {
      int m = m0 + wv * 32 + ms * 16 + jc;
#pragma unroll
      for (int c = 0; c < 3; ++c)
        atomicAdd(&rs[(size_t)c * NP + m], gcol[ms][c]);
    }
  }
}

// reciprocal in-place
__global__ __launch_bounds__(256) void recip_kernel(float* __restrict__ p, int nelem) {
  int i = blockIdx.x * 256 + threadIdx.x;
  if (i < nelem) p[i] = 1.0f / p[i];
}

// ================= tile_topk v2 (R22-verified): compute A once into LDS, row+col reduce =======
__global__ __launch_bounds__(256, 3) void tile_topk(
    const float2* __restrict__ Sbuf, const float* __restrict__ rinv,
    float* __restrict__ P) {
  __shared__ float2 tileS[32][129];  // 33024 B
  __shared__ float Ac[32][132];      // 16896 B
  __shared__ float rinL[3][32];
  __shared__ float rimL[3][128];

  const int b = blockIdx.y;
  int id = blockIdx.x;
  const int tid0 = id;
  int g = 0;
  while (id >= 4 * (8 - g)) { id -= 4 * (8 - g); ++g; }
  const int ni = 4 * g + id / (8 - g);
  const int mj = g + id % (8 - g);
  const int n0 = ni * TN;
  const int m0 = mj * TM;

  const int t = threadIdx.x;
  const float* rb = rinv + (size_t)b * 3 * NP;
  const float2* src = Sbuf + (size_t)(b * NTILE + tid0) * 32 * TM;
  float* Pp = P + ((size_t)(b * NTILE + tid0) * 160) * 9;

#pragma unroll
  for (int q = 0; q < 16; ++q) {
    int flat = q * 256 + t;
    tileS[flat >> 7][flat & 127] = src[flat];
  }
  if (t < 96) rinL[t >> 5][t & 31] = rb[(size_t)(t >> 5) * NP + n0 + (t & 31)];
#pragma unroll
  for (int q = 0; q < 2; ++q) {
    int flat = q * 256 + t;
    if (flat < 384)
      rimL[flat >> 7][flat & 127] = rb[(size_t)(flat >> 7) * NP + m0 + (flat & 127)];
  }
  __syncthreads();

#pragma unroll
  for (int c = 0; c < 3; ++c) {
#pragma unroll
    for (int q = 0; q < 16; ++q) {
      int flat = q * 256 + t;
      int row = flat >> 7, col = flat & 127;
      int n = n0 + row, m = m0 + col;
      float2 sv = tileS[row][col];
      float s = (c == 0) ? sv.x : (c == 1) ? sv.y : 0.5f * (sv.x + sv.y);
      float a = (m >= n) ? __expf(2.0f * s) * rinL[c][row] * rimL[c][col] : 0.f;
      Ac[row][col] = a;
    }
    __syncthreads();

    {
      int rl = t >> 3, cs = t & 7;
      float u0 = 0.f, u1 = 0.f, u2 = 0.f;
#pragma unroll
      for (int cc = 0; cc < 16; ++cc)
        top3_ins(u0, u1, u2, Ac[rl][cs * 16 + cc]);
#pragma unroll
      for (int off = 1; off < 8; off <<= 1) {
        float o0 = __shfl_xor(u0, off, 64);
        float o1 = __shfl_xor(u1, off, 64);
        float o2 = __shfl_xor(u2, off, 64);
        top3_ins(u0, u1, u2, o0);
        top3_ins(u0, u1, u2, o1);
        top3_ins(u0, u1, u2, o2);
      }
      if (cs == 0) {
        Pp[(size_t)rl * 9 + c * 3 + 0] = u0;
        Pp[(size_t)rl * 9 + c * 3 + 1] = u1;
        Pp[(size_t)rl * 9 + c * 3 + 2] = u2;
      }
    }
    {
      int cu = t >> 1, r0 = (t & 1) * 16;
      int m = m0 + cu;
      float u0 = 0.f, u1 = 0.f, u2 = 0.f;
#pragma unroll
      for (int rr = 0; rr < 16; ++rr) {
        int row = r0 + rr;
        if (n0 + row < m) top3_ins(u0, u1, u2, Ac[row][cu]);
      }
      float o0 = __shfl_xor(u0, 1, 64);
      float o1 = __shfl_xor(u1, 1, 64);
      float o2 = __shfl_xor(u2, 1, 64);
      top3_ins(u0, u1, u2, o0);
      top3_ins(u0, u1, u2, o1);
      top3_ins(u0, u1, u2, o2);
      if ((t & 1) == 0) {
        Pp[(size_t)(32 + cu) * 9 + c * 3 + 0] = u0;
        Pp[(size_t)(32 + cu) * 9 + c * 3 + 1] = u1;
        Pp[(size_t)(32 + cu) * 9 + c * 3 + 2] = u2;
      }
    }
    __syncthreads();
  }
}

// ================= merge (R21/R22-verified) =================
__global__ __launch_bounds__(256) void merge_kernel(
    const float* __restrict__ P, float* __restrict__ out) {
  int gid = blockIdx.x * 256 + threadIdx.x;  // < NB*3*NP
  int n = gid & (NP - 1);
  int tmp = gid >> 10;
  int c = tmp % 3;
  int b = tmp / 3;

  const float* Pb = P + (size_t)b * NTILE * 160 * 9;
  int g = n >> 7;
  int ni = n >> 5;
  int nl = n & 31;
  int ml = n & 127;

  float u0 = 0.f, u1 = 0.f, u2 = 0.f;
  int rbase = tile_base(g) + (ni - 4 * g) * (8 - g) - g;  // + mj
  for (int mj = g; mj < 8; ++mj) {
    const float* p = Pb + ((size_t)(rbase + mj) * 160 + nl) * 9 + c * 3;
    top3_ins(u0, u1, u2, p[0]);
    top3_ins(u0, u1, u2, p[1]);
    top3_ins(u0, u1, u2, p[2]);
  }
  for (int nii = 0; nii <= 4 * g + 3; ++nii) {
    int gg = nii >> 2;
    int tid = tile_base(gg) + (nii - 4 * gg) * (8 - gg) + (g - gg);
    const float* p = Pb + ((size_t)tid * 160 + 32 + ml) * 9 + c * 3;
    top3_ins(u0, u1, u2, p[0]);
    top3_ins(u0, u1, u2, p[1]);
    top3_ins(u0, u1, u2, p[2]);
  }

  int pr = n >> 5, pc = n & 31;
  int ii0, jj0, ii1 = -1, jj1 = -1;
  if (c == 0)      { ii0 = 2 * pr;     jj0 = 2 * pc; }
  else if (c == 1) { ii0 = 2 * pr + 1; jj0 = 2 * pc + 1; }
  else             { ii0 = 2 * pr;     jj0 = 2 * pc + 1;
                     ii1 = 2 * pr + 1; jj1 = 2 * pc; }
  out[(((size_t)b * 3 + 0) * NH + ii0) * NW + jj0] = u0;
  out[(((size_t)b * 3 + 1) * NH + ii0) * NW + jj0] = u1;
  out[(((size_t)b * 3 + 2) * NH + ii0) * NW + jj0] = u2;
  if (ii1 >= 0) {
    out[(((size_t)b * 3 + 0) * NH + ii1) * NW + jj1] = u0;
    out[(((size_t)b * 3 + 1) * NH + ii1) * NW + jj1] = u1;
    out[(((size_t)b * 3 + 2) * NH + ii1) * NW + jj1] = u2;
  }
}

// ================= FALLBACK PATH (verified fp32 vector) =================
__global__ __launch_bounds__(256) void prep_kernel(const float* __restrict__ x,
                                                   float* __restrict__ V) {
  int blk = blockIdx.x;
  int t = threadIdx.x;
  int b = blk >> 3;
  int c = (blk >> 2) & 1;
  int n = (blk & 3) * 256 + t;
  int i = 2 * (n >> 5) + c;
  int j = 2 * (n & 31) + c;
  const float* xp = x + (size_t)b * NCH * NH * NW + i * NW + j;
  float ss = 0.f;
#pragma unroll 8
  for (int ch = 0; ch < NCH; ++ch) {
    float v = xp[(size_t)ch * NH * NW];
    ss += v * v;
  }
  float r = 1.0f / fmaxf(sqrtf(ss), 1e-12f);
  float* vp = V + (((size_t)b * 2 + c) * NP + n) * NCH;
#pragma unroll 8
  for (int ch = 0; ch < NCH; ++ch) {
    vp[ch] = xp[(size_t)ch * NH * NW] * r;
  }
}

template <int PASS>
__global__ __launch_bounds__(256, 2) void corr_kernel(
    const float* __restrict__ V, const float* __restrict__ alpha_p,
    float* __restrict__ rsum_g, float* __restrict__ out) {
  __shared__ __align__(16) float As[2][TN][KP];
  __shared__ __align__(16) float Bs[2][TM][KP];

  const int b = blockIdx.y;
  const int n0 = blockIdx.x * TN;
  const int t = threadIdx.x;
  const int tx = t & 31;
  const int ty = t >> 5;
  const float alpha = *alpha_p;
  const float* Vb = V + (size_t)b * 2 * NP * NCH;

  float sm[3][4];
  float t0[3][4], t1[3][4], t2[3][4];
  float rin[3][4];
#pragma unroll
  for (int c = 0; c < 3; ++c)
#pragma unroll
    for (int i = 0; i < 4; ++i) {
      sm[c][i] = 0.f;
      t0[c][i] = 0.f; t1[c][i] = 0.f; t2[c][i] = 0.f;
    }
  if (PASS == 2) {
#pragma unroll
    for (int c = 0; c < 3; ++c)
#pragma unroll
      for (int i = 0; i < 4; ++i) {
        int n = n0 + ty * 4 + i;
        rin[c][i] = 1.0f / rsum_g[((size_t)b * 3 + c) * NP + n];
      }
  }

  for (int mc = 0; mc < NP / TM; ++mc) {
    const int m0 = mc * TM;
    float acc[2][4][4];
#pragma unroll
    for (int c = 0; c < 2; ++c)
#pragma unroll
      for (int i = 0; i < 4; ++i)
#pragma unroll
        for (int j = 0; j < 4; ++j) acc[c][i][j] = 0.f;

    for (int k0 = 0; k0 < NCH; k0 += KC) {
      __syncthreads();
#pragma unroll
      for (int q = 0; q < 2; ++q) {
        int flat = q * 256 + t;
        int c = flat >> 8;
        int rem = flat & 255;
        int row = rem >> 3;
        int kgx = rem & 7;
        float4 v4 = *(const float4*)(Vb + ((size_t)c * NP + n0 + row) * NCH + k0 + kgx * 4);
        *(float4*)&As[c][row][kgx * 4] = v4;
      }
#pragma unroll
      for (int q = 0; q < 8; ++q) {
        int flat = q * 256 + t;
        int c = flat >> 10;
        int rem = flat & 1023;
        int row = rem >> 3;
        int kgx = rem & 7;
        float4 v4 = *(const float4*)(Vb + ((size_t)c * NP + m0 + row) * NCH + k0 + kgx * 4);
        *(float4*)&Bs[c][row][kgx * 4] = v4;
      }
      __syncthreads();

      for (int kgx = 0; kgx < KC; kgx += 4) {
        float4 a4[2][4], b4[2][4];
#pragma unroll
        for (int c = 0; c < 2; ++c)
#pragma unroll
          for (int i = 0; i < 4; ++i)
            a4[c][i] = *(const float4*)&As[c][ty * 4 + i][kgx];
#pragma unroll
        for (int c = 0; c < 2; ++c)
#pragma unroll
          for (int j = 0; j < 4; ++j)
            b4[c][j] = *(const float4*)&Bs[c][tx + 32 * j][kgx];
#pragma unroll
        for (int c = 0; c < 2; ++c)
#pragma unroll
          for (int i = 0; i < 4; ++i)
#pragma unroll
            for (int j = 0; j < 4; ++j)
              acc[c][i][j] += dot4(a4[c][i], b4[c][j]);
      }
    }

    float rim[3][4];
    if (PASS == 2) {
#pragma unroll
      for (int c = 0; c < 3; ++c)
#pragma unroll
        for (int j = 0; j < 4; ++j) {
          int m = m0 + tx + 32 * j;
          rim[c][j] = 1.0f / rsum_g[((size_t)b * 3 + c) * NP + m];
        }
    }
#pragma unroll
    for (int i = 0; i < 4; ++i) {
      int n = n0 + ty * 4 + i;
      int nr = n >> 5, nc = n & 31;
      float s[3][4];
#pragma unroll
      for (int j = 0; j < 4; ++j) {
        int m = m0 + tx + 32 * j;
        int dr = nr - (m >> 5);
        int dc = nc - (m & 31);
        float gq = __expf(-(float)(dr * dr + dc * dc) * 0.1953125f);
        float wgt = (1.0f - gq) * alpha;
        float s0v = acc[0][i][j] * wgt;
        float s1v = acc[1][i][j] * wgt;
        s[0][j] = s0v; s[1][j] = s1v; s[2][j] = 0.5f * (s0v + s1v);
      }
      if (PASS == 1) {
#pragma unroll
        for (int c = 0; c < 3; ++c) {
          sm[c][i] += __expf(s[c][0]) + __expf(s[c][1]) +
                      __expf(s[c][2]) + __expf(s[c][3]);
        }
      } else {
#pragma unroll
        for (int c = 0; c < 3; ++c) {
#pragma unroll
          for (int j = 0; j < 4; ++j) {
            float a = __expf(2.0f * s[c][j]) * rin[c][i] * rim[c][j];
            top3_ins(t0[c][i], t1[c][i], t2[c][i], a);
          }
        }
      }
    }
  }

  if (PASS == 1) {
#pragma unroll
    for (int off = 1; off < 32; off <<= 1) {
#pragma unroll
      for (int c = 0; c < 3; ++c)
#pragma unroll
        for (int i = 0; i < 4; ++i)
          sm[c][i] += __shfl_xor(sm[c][i], off, 64);
    }
    if (tx == 0) {
#pragma unroll
      for (int c = 0; c < 3; ++c)
#pragma unroll
        for (int i = 0; i < 4; ++i) {
          int n = n0 + ty * 4 + i;
          rsum_g[((size_t)b * 3 + c) * NP + n] = sm[c][i];
        }
    }
  } else {
#pragma unroll
    for (int off = 1; off < 32; off <<= 1) {
#pragma unroll
      for (int c = 0; c < 3; ++c)
#pragma unroll
        for (int i = 0; i < 4; ++i) {
          float o0 = __shfl_xor(t0[c][i], off, 64);
          float o1 = __shfl_xor(t1[c][i], off, 64);
          float o2 = __shfl_xor(t2[c][i], off, 64);
          top3_ins(t0[c][i], t1[c][i], t2[c][i], o0);
          top3_ins(t0[c][i], t1[c][i], t2[c][i], o1);
          top3_ins(t0[c][i], t1[c][i], t2[c][i], o2);
        }
    }
    if (tx == 0) {
#pragma unroll
      for (int c = 0; c < 3; ++c)
#pragma unroll
        for (int i = 0; i < 4; ++i) {
          int n = n0 + ty * 4 + i;
          int pr = n >> 5, pc = n & 31;
          float v0 = t0[c][i], v1 = t1[c][i], v2 = t2[c][i];
          int ii0, jj0, ii1 = -1, jj1 = -1;
          if (c == 0)      { ii0 = 2 * pr;     jj0 = 2 * pc; }
          else if (c == 1) { ii0 = 2 * pr + 1; jj0 = 2 * pc + 1; }
          else             { ii0 = 2 * pr;     jj0 = 2 * pc + 1;
                             ii1 = 2 * pr + 1; jj1 = 2 * pc; }
          out[(((size_t)b * 3 + 0) * NH + ii0) * NW + jj0] = v0;
          out[(((size_t)b * 3 + 1) * NH + ii0) * NW + jj0] = v1;
          out[(((size_t)b * 3 + 2) * NH + ii0) * NW + jj0] = v2;
          if (ii1 >= 0) {
            out[(((size_t)b * 3 + 0) * NH + ii1) * NW + jj1] = v0;
            out[(((size_t)b * 3 + 1) * NH + ii1) * NW + jj1] = v1;
            out[(((size_t)b * 3 + 2) * NH + ii1) * NW + jj1] = v2;
          }
        }
    }
  }
}

extern "C" void kernel_launch(void* const* d_in, const int* in_sizes, int n_in,
                              void* d_out, int out_size, void* d_ws, size_t ws_size,
                              hipStream_t stream) {
  const float* x = (const float*)d_in[0];
  const float* alpha = (const float*)d_in[1];
  float* out = (float*)d_out;

  const size_t nVsU = (size_t)NB * 6 * NP * NCH;          // ushorts: 25.2 MB
  const size_t nRs = (size_t)NB * 3 * NP;                 // floats
  const size_t nSbuf = (size_t)NB * NTILE * 32 * TM;      // float2 slots: 75.5 MB
  const size_t nP = (size_t)NB * NTILE * 160 * 9;         // floats: 13.3 MB

  ushort* Vs = (ushort*)d_ws;
  float* rsum = (float*)(Vs + nVsU);
  float2* Sbuf = (float2*)(rsum + nRs);
  float* P = (float*)(Sbuf + nSbuf);

  const size_t need_bytes = nVsU * 2 + nRs * 4 + nSbuf * 8 + nP * 4;

  if (ws_size >= need_bytes) {
    prep_split<<<512, 256, 0, stream>>>(x, Vs, rsum);
    gemm_mfma<<<NTILE * NB, 256, 0, stream>>>(Vs, alpha, Sbuf, rsum);
    recip_kernel<<<(NB * 3 * NP + 255) / 256, 256, 0, stream>>>(rsum, NB * 3 * NP);
    tile_topk<<<dim3(NTILE, NB), 256, 0, stream>>>(Sbuf, rsum, P);
    merge_kernel<<<(NB * 3 * NP) / 256, 256, 0, stream>>>(P, out);
  } else {
    float* V = (float*)d_ws;
    float* rsum_f = V + (size_t)NB * 2 * NP * NCH;
    prep_kernel<<<128, 256, 0, stream>>>(x, V);
    corr_kernel<1><<<dim3(NP / TN, NB), 256, 0, stream>>>(V, alpha, rsum_f, out);
    corr_kernel<2><<<dim3(NP / TN, NB), 256, 0, stream>>>(V, alpha, rsum_f, out);
  }
}

// Round 25
// 145.155 us; speedup vs baseline: 1.6844x; 1.6844x over previous
//
#include <hip/hip_runtime.h>
#include <math.h>

#define NB 16
#define NCH 128
#define NH 64
#define NW 64
#define NP 1024

#define TN 32
#define TM 128
#define KC 32
#define KP 36    // fp32 fallback pad
#define PK 40    // bf16 staging pad (ushorts): 80B rows, 16B-aligned (b128 ops); 4-way read conflict accepted

#define NTILE 144  // symmetric tile count

typedef __attribute__((ext_vector_type(8))) short short8v;
typedef __attribute__((ext_vector_type(4))) float f32x4;

__device__ __forceinline__ float med3(float a, float b, float c) {
  return __builtin_amdgcn_fmed3f(a, b, c);
}
__device__ __forceinline__ void top3_ins(float& t0, float& t1, float& t2, float a) {
  float n0 = fmaxf(t0, a);
  float n1 = med3(a, t0, t1);
  float n2 = med3(a, t1, t2);
  t0 = n0; t1 = n1; t2 = n2;
}
__device__ __forceinline__ float dot4(float4 a, float4 b) {
  return a.x * b.x + a.y * b.y + a.z * b.z + a.w * b.w;
}
__device__ __forceinline__ ushort f2bf(float f) {  // RNE bf16
  unsigned u = __float_as_uint(f);
  unsigned r = (u + 0x7FFFu + ((u >> 16) & 1u)) >> 16;
  return (ushort)r;
}
__device__ __forceinline__ float bf2f(ushort h) {
  return __uint_as_float(((unsigned)h) << 16);
}
__device__ __forceinline__ int tile_base(int g) {  // sum_{h<g} 4*(8-h)
  return 32 * g - 2 * g * (g - 1);
}

// ---------------- prep_split (R16-verified) ----------------
__global__ __launch_bounds__(256) void prep_split(const float* __restrict__ x,
                                                  ushort* __restrict__ Vs,
                                                  float* __restrict__ rsum) {
  int blk = blockIdx.x;
  int t = threadIdx.x;
  int gid = blk * 256 + t;
  if (gid < NB * 3 * NP) rsum[gid] = 0.f;

  int b = blk >> 5;
  int c = (blk >> 4) & 1;
  int ng = blk & 15;
  int nl = t >> 2;
  int kq = t & 3;
  int n = ng * 64 + nl;
  int i = 2 * (n >> 5) + c;
  int j = 2 * (n & 31) + c;
  const float* xp = x + (size_t)b * NCH * NH * NW + i * NW + j;

  float v[32];
#pragma unroll
  for (int e = 0; e < 32; ++e)
    v[e] = xp[(size_t)(kq * 32 + e) * NH * NW];

  float ss = 0.f;
#pragma unroll
  for (int e = 0; e < 32; ++e) ss += v[e] * v[e];
  ss += __shfl_xor(ss, 1, 64);
  ss += __shfl_xor(ss, 2, 64);
  float r = 1.0f / fmaxf(sqrtf(ss), 1e-12f);

  size_t base = ((size_t)(b * 2 + c) * 3) * NP * NCH + (size_t)n * NCH + kq * 32;
  ushort* p1 = Vs + base;
  ushort* p2 = Vs + base + (size_t)NP * NCH;
  ushort* p3 = Vs + base + (size_t)2 * NP * NCH;
#pragma unroll
  for (int kg2 = 0; kg2 < 4; ++kg2) {
    ushort h1[8], h2[8], h3[8];
#pragma unroll
    for (int e = 0; e < 8; ++e) {
      float vv = v[kg2 * 8 + e] * r;
      ushort a = f2bf(vv);
      float r1 = vv - bf2f(a);
      ushort bq = f2bf(r1);
      float r2 = r1 - bf2f(bq);
      ushort cq = f2bf(r2);
      h1[e] = a; h2[e] = bq; h3[e] = cq;
    }
    *(float4*)(p1 + kg2 * 8) = *(float4*)h1;
    *(float4*)(p2 + kg2 * 8) = *(float4*)h2;
    *(float4*)(p3 + kg2 * 8) = *(float4*)h3;
  }
}

// ================= MFMA bf16x3 sym GEMM (R21/R22-verified): packed upper Sbuf + fused sums ====
__global__ __launch_bounds__(256, 4) void gemm_mfma(
    const ushort* __restrict__ Vs, const float* __restrict__ alpha_p,
    float2* __restrict__ Sbuf, float* __restrict__ rsum) {
  __shared__ __align__(16) char smem[3 * 32 * PK * 2 + 3 * 128 * PK * 2];  // 38400 B
  ushort (*A_s)[32][PK] = reinterpret_cast<ushort(*)[32][PK]>(smem);
  ushort (*B_s)[128][PK] =
      reinterpret_cast<ushort(*)[128][PK]>(smem + 3 * 32 * PK * 2);

  int wg = blockIdx.x;
  int xcd = wg & 7;
  int jj = wg >> 3;
  int half = (jj >= NTILE) ? 1 : 0;
  const int b = 2 * xcd + half;
  int id = jj - half * NTILE;
  const int tid0 = id;                     // packed tile index
  int g = 0;
  while (id >= 4 * (8 - g)) { id -= 4 * (8 - g); ++g; }
  const int ni = 4 * g + id / (8 - g);
  const int mj = g + id % (8 - g);
  const int n0 = ni * TN;
  const int m0 = mj * TM;

  const int t = threadIdx.x;
  const int lane = t & 63, wv = t >> 6;
  const int jc = lane & 15, kg = lane >> 4;
  const float alpha = *alpha_p;
  const ushort* Vsb = Vs + (size_t)b * 6 * NP * NCH;
  float* rs = rsum + (size_t)b * 3 * NP;

  f32x4 acc[2][2][2];
#pragma unroll
  for (int c = 0; c < 2; ++c)
#pragma unroll
    for (int i = 0; i < 2; ++i)
#pragma unroll
      for (int j = 0; j < 2; ++j) acc[c][i][j] = (f32x4){0.f, 0.f, 0.f, 0.f};

#pragma unroll
  for (int c = 0; c < 2; ++c) {
    for (int k0 = 0; k0 < NCH; k0 += KC) {
      __syncthreads();
#pragma unroll
      for (int q = 0; q < 2; ++q) {
        int flat = q * 256 + t;
        if (flat < 384) {
          int p = flat >> 7;
          int rem = flat & 127;
          int row = rem >> 2, u = rem & 3;
          const ushort* src = Vsb + ((size_t)(c * 3 + p) * NP + n0 + row) * NCH + k0 + u * 8;
          *(float4*)&A_s[p][row][u * 8] = *(const float4*)src;
        }
      }
#pragma unroll
      for (int q = 0; q < 6; ++q) {
        int flat = q * 256 + t;
        int p = flat >> 9;
        int rem = flat & 511;
        int row = rem >> 2, u = rem & 3;
        const ushort* src = Vsb + ((size_t)(c * 3 + p) * NP + m0 + row) * NCH + k0 + u * 8;
        *(float4*)&B_s[p][row][u * 8] = *(const float4*)src;
      }
      __syncthreads();

      short8v a1n0 = *(const short8v*)&A_s[0][jc][kg * 8];
      short8v a1n1 = *(const short8v*)&A_s[0][16 + jc][kg * 8];
      short8v a2n0 = *(const short8v*)&A_s[1][jc][kg * 8];
      short8v a2n1 = *(const short8v*)&A_s[1][16 + jc][kg * 8];
      short8v a3n0 = *(const short8v*)&A_s[2][jc][kg * 8];
      short8v a3n1 = *(const short8v*)&A_s[2][16 + jc][kg * 8];
      {
        short8v b0 = *(const short8v*)&B_s[0][wv * 32 + jc][kg * 8];
        short8v b1 = *(const short8v*)&B_s[0][wv * 32 + 16 + jc][kg * 8];
        acc[c][0][0] = __builtin_amdgcn_mfma_f32_16x16x32_bf16(a1n0, b0, acc[c][0][0], 0, 0, 0);
        acc[c][1][0] = __builtin_amdgcn_mfma_f32_16x16x32_bf16(a1n1, b0, acc[c][1][0], 0, 0, 0);
        acc[c][0][1] = __builtin_amdgcn_mfma_f32_16x16x32_bf16(a1n0, b1, acc[c][0][1], 0, 0, 0);
        acc[c][1][1] = __builtin_amdgcn_mfma_f32_16x16x32_bf16(a1n1, b1, acc[c][1][1], 0, 0, 0);
        acc[c][0][0] = __builtin_amdgcn_mfma_f32_16x16x32_bf16(a2n0, b0, acc[c][0][0], 0, 0, 0);
        acc[c][1][0] = __builtin_amdgcn_mfma_f32_16x16x32_bf16(a2n1, b0, acc[c][1][0], 0, 0, 0);
        acc[c][0][1] = __builtin_amdgcn_mfma_f32_16x16x32_bf16(a2n0, b1, acc[c][0][1], 0, 0, 0);
        acc[c][1][1] = __builtin_amdgcn_mfma_f32_16x16x32_bf16(a2n1, b1, acc[c][1][1], 0, 0, 0);
        acc[c][0][0] = __builtin_amdgcn_mfma_f32_16x16x32_bf16(a3n0, b0, acc[c][0][0], 0, 0, 0);
        acc[c][1][0] = __builtin_amdgcn_mfma_f32_16x16x32_bf16(a3n1, b0, acc[c][1][0], 0, 0, 0);
        acc[c][0][1] = __builtin_amdgcn_mfma_f32_16x16x32_bf16(a3n0, b1, acc[c][0][1], 0, 0, 0);
        acc[c][1][1] = __builtin_amdgcn_mfma_f32_16x16x32_bf16(a3n1, b1, acc[c][1][1], 0, 0, 0);
      }
      {
        short8v b0 = *(const short8v*)&B_s[1][wv * 32 + jc][kg * 8];
        short8v b1 = *(const short8v*)&B_s[1][wv * 32 + 16 + jc][kg * 8];
        acc[c][0][0] = __builtin_amdgcn_mfma_f32_16x16x32_bf16(a1n0, b0, acc[c][0][0], 0, 0, 0);
        acc[c][1][0] = __builtin_amdgcn_mfma_f32_16x16x32_bf16(a1n1, b0, acc[c][1][0], 0, 0, 0);
        acc[c][0][1] = __builtin_amdgcn_mfma_f32_16x16x32_bf16(a1n0, b1, acc[c][0][1], 0, 0, 0);
        acc[c][1][1] = __builtin_amdgcn_mfma_f32_16x16x32_bf16(a1n1, b1, acc[c][1][1], 0, 0, 0);
        acc[c][0][0] = __builtin_amdgcn_mfma_f32_16x16x32_bf16(a2n0, b0, acc[c][0][0], 0, 0, 0);
        acc[c][1][0] = __builtin_amdgcn_mfma_f32_16x16x32_bf16(a2n1, b0, acc[c][1][0], 0, 0, 0);
        acc[c][0][1] = __builtin_amdgcn_mfma_f32_16x16x32_bf16(a2n0, b1, acc[c][0][1], 0, 0, 0);
        acc[c][1][1] = __builtin_amdgcn_mfma_f32_16x16x32_bf16(a2n1, b1, acc[c][1][1], 0, 0, 0);
      }
      {
        short8v b0 = *(const short8v*)&B_s[2][wv * 32 + jc][kg * 8];
        short8v b1 = *(const short8v*)&B_s[2][wv * 32 + 16 + jc][kg * 8];
        acc[c][0][0] = __builtin_amdgcn_mfma_f32_16x16x32_bf16(a1n0, b0, acc[c][0][0], 0, 0, 0);
        acc[c][1][0] = __builtin_amdgcn_mfma_f32_16x16x32_bf16(a1n1, b0, acc[c][1][0], 0, 0, 0);
        acc[c][0][1] = __builtin_amdgcn_mfma_f32_16x16x32_bf16(a1n0, b1, acc[c][0][1], 0, 0, 0);
        acc[c][1][1] = __builtin_amdgcn_mfma_f32_16x16x32_bf16(a1n1, b1, acc[c][1][1], 0, 0, 0);
      }
    }
  }

  // ---- epilogue: tile write (m>=n) + row/col exp partials ----
  float e[2][4][3];
  float gcol[2][3];
#pragma unroll
  for (int ns = 0; ns < 2; ++ns)
#pragma unroll
    for (int r = 0; r < 4; ++r)
#pragma unroll
      for (int c = 0; c < 3; ++c) e[ns][r][c] = 0.f;
#pragma unroll
  for (int ms = 0; ms < 2; ++ms)
#pragma unroll
    for (int c = 0; c < 3; ++c) gcol[ms][c] = 0.f;

#pragma unroll
  for (int ns = 0; ns < 2; ++ns) {
#pragma unroll
    for (int r = 0; r < 4; ++r) {
      int nl = ns * 16 + kg * 4 + r;
      int n = n0 + nl;
      int nr = n >> 5, nc = n & 31;
      float2* rowp = Sbuf + ((size_t)(b * NTILE + tid0) * 32 + nl) * TM;
#pragma unroll
      for (int ms = 0; ms < 2; ++ms) {
        int ml = wv * 32 + ms * 16 + jc;
        int m = m0 + ml;
        int dr = nr - (m >> 5);
        int dc = nc - (m & 31);
        float gss = __expf(-(float)(dr * dr + dc * dc) * 0.1953125f);
        float wgt = (1.0f - gss) * alpha;
        float s0 = acc[0][ns][ms][r] * wgt;
        float s1 = acc[1][ns][ms][r] * wgt;
        float e0 = __expf(s0);
        float e1 = __expf(s1);
        float e2 = __expf(0.5f * (s0 + s1));
        if (m >= n) {
          rowp[ml] = make_float2(s0, s1);
          e[ns][r][0] += e0; e[ns][r][1] += e1; e[ns][r][2] += e2;
        }
        if (m > n) { gcol[ms][0] += e0; gcol[ms][1] += e1; gcol[ms][2] += e2; }
      }
    }
  }
#pragma unroll
  for (int off = 1; off < 16; off <<= 1) {
#pragma unroll
    for (int ns = 0; ns < 2; ++ns)
#pragma unroll
      for (int r = 0; r < 4; ++r)
#pragma unroll
        for (int c = 0; c < 3; ++c)
          e[ns][r][c] += __shfl_xor(e[ns][r][c], off, 64);
  }
  if (jc == 0) {
#pragma unroll
    for (int ns = 0; ns < 2; ++ns)
#pragma unroll
      for (int r = 0; r < 4; ++r)
#pragma unroll
        for (int c = 0; c < 3; ++c)
          atomicAdd(&rs[(size_t)c * NP + (n0 + ns * 16 + kg * 4 + r)], e[ns][r][c]);
  }
#pragma unroll
  for (int off = 16; off < 64; off <<= 1) {
#pragma unroll
    for (int ms = 0; ms < 2; ++ms)
#pragma unroll
      for (int c = 0; c < 3; ++c)
        gcol[ms][c] += __shfl_xor(gcol[ms][c], off, 64);
  }
  if (kg == 0) {
#pragma unroll
    for (int ms = 0; ms < 2; ++ms) {
      int m = m0 + wv * 32 + ms * 16 + jc;
#pragma unroll
      for (int c = 0; c < 3; ++c)
        atomicAdd(&rs[(size_t)c * NP + m], gcol[ms][c]);
    }
  }
}

// reciprocal in-place
__global__ __launch_bounds__(256) void recip_kernel(float* __restrict__ p, int nelem) {
  int i = blockIdx.x * 256 + threadIdx.x;
  if (i < nelem) p[i] = 1.0f / p[i];
}

// ================= tile_topk v2 (R22-verified): compute A once into LDS, row+col reduce =======
__global__ __launch_bounds__(256, 3) void tile_topk(
    const float2* __restrict__ Sbuf, const float* __restrict__ rinv,
    float* __restrict__ P) {
  __shared__ float2 tileS[32][129];  // 33024 B
  __shared__ float Ac[32][132];      // 16896 B
  __shared__ float rinL[3][32];
  __shared__ float rimL[3][128];

  const int b = blockIdx.y;
  int id = blockIdx.x;
  const int tid0 = id;
  int g = 0;
  while (id >= 4 * (8 - g)) { id -= 4 * (8 - g); ++g; }
  const int ni = 4 * g + id / (8 - g);
  const int mj = g + id % (8 - g);
  const int n0 = ni * TN;
  const int m0 = mj * TM;

  const int t = threadIdx.x;
  const float* rb = rinv + (size_t)b * 3 * NP;
  const float2* src = Sbuf + (size_t)(b * NTILE + tid0) * 32 * TM;
  float* Pp = P + ((size_t)(b * NTILE + tid0) * 160) * 9;

#pragma unroll
  for (int q = 0; q < 16; ++q) {
    int flat = q * 256 + t;
    tileS[flat >> 7][flat & 127] = src[flat];
  }
  if (t < 96) rinL[t >> 5][t & 31] = rb[(size_t)(t >> 5) * NP + n0 + (t & 31)];
#pragma unroll
  for (int q = 0; q < 2; ++q) {
    int flat = q * 256 + t;
    if (flat < 384)
      rimL[flat >> 7][flat & 127] = rb[(size_t)(flat >> 7) * NP + m0 + (flat & 127)];
  }
  __syncthreads();

#pragma unroll
  for (int c = 0; c < 3; ++c) {
#pragma unroll
    for (int q = 0; q < 16; ++q) {
      int flat = q * 256 + t;
      int row = flat >> 7, col = flat & 127;
      int n = n0 + row, m = m0 + col;
      float2 sv = tileS[row][col];
      float s = (c == 0) ? sv.x : (c == 1) ? sv.y : 0.5f * (sv.x + sv.y);
      float a = (m >= n) ? __expf(2.0f * s) * rinL[c][row] * rimL[c][col] : 0.f;
      Ac[row][col] = a;
    }
    __syncthreads();

    {
      int rl = t >> 3, cs = t & 7;
      float u0 = 0.f, u1 = 0.f, u2 = 0.f;
#pragma unroll
      for (int cc = 0; cc < 16; ++cc)
        top3_ins(u0, u1, u2, Ac[rl][cs * 16 + cc]);
#pragma unroll
      for (int off = 1; off < 8; off <<= 1) {
        float o0 = __shfl_xor(u0, off, 64);
        float o1 = __shfl_xor(u1, off, 64);
        float o2 = __shfl_xor(u2, off, 64);
        top3_ins(u0, u1, u2, o0);
        top3_ins(u0, u1, u2, o1);
        top3_ins(u0, u1, u2, o2);
      }
      if (cs == 0) {
        Pp[(size_t)rl * 9 + c * 3 + 0] = u0;
        Pp[(size_t)rl * 9 + c * 3 + 1] = u1;
        Pp[(size_t)rl * 9 + c * 3 + 2] = u2;
      }
    }
    {
      int cu = t >> 1, r0 = (t & 1) * 16;
      int m = m0 + cu;
      float u0 = 0.f, u1 = 0.f, u2 = 0.f;
#pragma unroll
      for (int rr = 0; rr < 16; ++rr) {
        int row = r0 + rr;
        if (n0 + row < m) top3_ins(u0, u1, u2, Ac[row][cu]);
      }
      float o0 = __shfl_xor(u0, 1, 64);
      float o1 = __shfl_xor(u1, 1, 64);
      float o2 = __shfl_xor(u2, 1, 64);
      top3_ins(u0, u1, u2, o0);
      top3_ins(u0, u1, u2, o1);
      top3_ins(u0, u1, u2, o2);
      if ((t & 1) == 0) {
        Pp[(size_t)(32 + cu) * 9 + c * 3 + 0] = u0;
        Pp[(size_t)(32 + cu) * 9 + c * 3 + 1] = u1;
        Pp[(size_t)(32 + cu) * 9 + c * 3 + 2] = u2;
      }
    }
    __syncthreads();
  }
}

// ================= merge (R21/R22-verified) =================
__global__ __launch_bounds__(256) void merge_kernel(
    const float* __restrict__ P, float* __restrict__ out) {
  int gid = blockIdx.x * 256 + threadIdx.x;  // < NB*3*NP
  int n = gid & (NP - 1);
  int tmp = gid >> 10;
  int c = tmp % 3;
  int b = tmp / 3;

  const float* Pb = P + (size_t)b * NTILE * 160 * 9;
  int g = n >> 7;
  int ni = n >> 5;
  int nl = n & 31;
  int ml = n & 127;

  float u0 = 0.f, u1 = 0.f, u2 = 0.f;
  int rbase = tile_base(g) + (ni - 4 * g) * (8 - g) - g;  // + mj
  for (int mj = g; mj < 8; ++mj) {
    const float* p = Pb + ((size_t)(rbase + mj) * 160 + nl) * 9 + c * 3;
    top3_ins(u0, u1, u2, p[0]);
    top3_ins(u0, u1, u2, p[1]);
    top3_ins(u0, u1, u2, p[2]);
  }
  for (int nii = 0; nii <= 4 * g + 3; ++nii) {
    int gg = nii >> 2;
    int tid = tile_base(gg) + (nii - 4 * gg) * (8 - gg) + (g - gg);
    const float* p = Pb + ((size_t)tid * 160 + 32 + ml) * 9 + c * 3;
    top3_ins(u0, u1, u2, p[0]);
    top3_ins(u0, u1, u2, p[1]);
    top3_ins(u0, u1, u2, p[2]);
  }

  int pr = n >> 5, pc = n & 31;
  int ii0, jj0, ii1 = -1, jj1 = -1;
  if (c == 0)      { ii0 = 2 * pr;     jj0 = 2 * pc; }
  else if (c == 1) { ii0 = 2 * pr + 1; jj0 = 2 * pc + 1; }
  else             { ii0 = 2 * pr;     jj0 = 2 * pc + 1;
                     ii1 = 2 * pr + 1; jj1 = 2 * pc; }
  out[(((size_t)b * 3 + 0) * NH + ii0) * NW + jj0] = u0;
  out[(((size_t)b * 3 + 1) * NH + ii0) * NW + jj0] = u1;
  out[(((size_t)b * 3 + 2) * NH + ii0) * NW + jj0] = u2;
  if (ii1 >= 0) {
    out[(((size_t)b * 3 + 0) * NH + ii1) * NW + jj1] = u0;
    out[(((size_t)b * 3 + 1) * NH + ii1) * NW + jj1] = u1;
    out[(((size_t)b * 3 + 2) * NH + ii1) * NW + jj1] = u2;
  }
}

// ================= FALLBACK PATH (verified fp32 vector) =================
__global__ __launch_bounds__(256) void prep_kernel(const float* __restrict__ x,
                                                   float* __restrict__ V) {
  int blk = blockIdx.x;
  int t = threadIdx.x;
  int b = blk >> 3;
  int c = (blk >> 2) & 1;
  int n = (blk & 3) * 256 + t;
  int i = 2 * (n >> 5) + c;
  int j = 2 * (n & 31) + c;
  const float* xp = x + (size_t)b * NCH * NH * NW + i * NW + j;
  float ss = 0.f;
#pragma unroll 8
  for (int ch = 0; ch < NCH; ++ch) {
    float v = xp[(size_t)ch * NH * NW];
    ss += v * v;
  }
  float r = 1.0f / fmaxf(sqrtf(ss), 1e-12f);
  float* vp = V + (((size_t)b * 2 + c) * NP + n) * NCH;
#pragma unroll 8
  for (int ch = 0; ch < NCH; ++ch) {
    vp[ch] = xp[(size_t)ch * NH * NW] * r;
  }
}

template <int PASS>
__global__ __launch_bounds__(256, 2) void corr_kernel(
    const float* __restrict__ V, const float* __restrict__ alpha_p,
    float* __restrict__ rsum_g, float* __restrict__ out) {
  __shared__ __align__(16) float As[2][TN][KP];
  __shared__ __align__(16) float Bs[2][TM][KP];

  const int b = blockIdx.y;
  const int n0 = blockIdx.x * TN;
  const int t = threadIdx.x;
  const int tx = t & 31;
  const int ty = t >> 5;
  const float alpha = *alpha_p;
  const float* Vb = V + (size_t)b * 2 * NP * NCH;

  float sm[3][4];
  float t0[3][4], t1[3][4], t2[3][4];
  float rin[3][4];
#pragma unroll
  for (int c = 0; c < 3; ++c)
#pragma unroll
    for (int i = 0; i < 4; ++i) {
      sm[c][i] = 0.f;
      t0[c][i] = 0.f; t1[c][i] = 0.f; t2[c][i] = 0.f;
    }
  if (PASS == 2) {
#pragma unroll
    for (int c = 0; c < 3; ++c)
#pragma unroll
      for (int i = 0; i < 4; ++i) {
        int n = n0 + ty * 4 + i;
        rin[c][i] = 1.0f / rsum_g[((size_t)b * 3 + c) * NP + n];
      }
  }

  for (int mc = 0; mc < NP / TM; ++mc) {
    const int m0 = mc * TM;
    float acc[2][4][4];
#pragma unroll
    for (int c = 0; c < 2; ++c)
#pragma unroll
      for (int i = 0; i < 4; ++i)
#pragma unroll
        for (int j = 0; j < 4; ++j) acc[c][i][j] = 0.f;

    for (int k0 = 0; k0 < NCH; k0 += KC) {
      __syncthreads();
#pragma unroll
      for (int q = 0; q < 2; ++q) {
        int flat = q * 256 + t;
        int c = flat >> 8;
        int rem = flat & 255;
        int row = rem >> 3;
        int kgx = rem & 7;
        float4 v4 = *(const float4*)(Vb + ((size_t)c * NP + n0 + row) * NCH + k0 + kgx * 4);
        *(float4*)&As[c][row][kgx * 4] = v4;
      }
#pragma unroll
      for (int q = 0; q < 8; ++q) {
        int flat = q * 256 + t;
        int c = flat >> 10;
        int rem = flat & 1023;
        int row = rem >> 3;
        int kgx = rem & 7;
        float4 v4 = *(const float4*)(Vb + ((size_t)c * NP + m0 + row) * NCH + k0 + kgx * 4);
        *(float4*)&Bs[c][row][kgx * 4] = v4;
      }
      __syncthreads();

      for (int kgx = 0; kgx < KC; kgx += 4) {
        float4 a4[2][4], b4[2][4];
#pragma unroll
        for (int c = 0; c < 2; ++c)
#pragma unroll
          for (int i = 0; i < 4; ++i)
            a4[c][i] = *(const float4*)&As[c][ty * 4 + i][kgx];
#pragma unroll
        for (int c = 0; c < 2; ++c)
#pragma unroll
          for (int j = 0; j < 4; ++j)
            b4[c][j] = *(const float4*)&Bs[c][tx + 32 * j][kgx];
#pragma unroll
        for (int c = 0; c < 2; ++c)
#pragma unroll
          for (int i = 0; i < 4; ++i)
#pragma unroll
            for (int j = 0; j < 4; ++j)
              acc[c][i][j] += dot4(a4[c][i], b4[c][j]);
      }
    }

    float rim[3][4];
    if (PASS == 2) {
#pragma unroll
      for (int c = 0; c < 3; ++c)
#pragma unroll
        for (int j = 0; j < 4; ++j) {
          int m = m0 + tx + 32 * j;
          rim[c][j] = 1.0f / rsum_g[((size_t)b * 3 + c) * NP + m];
        }
    }
#pragma unroll
    for (int i = 0; i < 4; ++i) {
      int n = n0 + ty * 4 + i;
      int nr = n >> 5, nc = n & 31;
      float s[3][4];
#pragma unroll
      for (int j = 0; j < 4; ++j) {
        int m = m0 + tx + 32 * j;
        int dr = nr - (m >> 5);
        int dc = nc - (m & 31);
        float gq = __expf(-(float)(dr * dr + dc * dc) * 0.1953125f);
        float wgt = (1.0f - gq) * alpha;
        float s0v = acc[0][i][j] * wgt;
        float s1v = acc[1][i][j] * wgt;
        s[0][j] = s0v; s[1][j] = s1v; s[2][j] = 0.5f * (s0v + s1v);
      }
      if (PASS == 1) {
#pragma unroll
        for (int c = 0; c < 3; ++c) {
          sm[c][i] += __expf(s[c][0]) + __expf(s[c][1]) +
                      __expf(s[c][2]) + __expf(s[c][3]);
        }
      } else {
#pragma unroll
        for (int c = 0; c < 3; ++c) {
#pragma unroll
          for (int j = 0; j < 4; ++j) {
            float a = __expf(2.0f * s[c][j]) * rin[c][i] * rim[c][j];
            top3_ins(t0[c][i], t1[c][i], t2[c][i], a);
          }
        }
      }
    }
  }

  if (PASS == 1) {
#pragma unroll
    for (int off = 1; off < 32; off <<= 1) {
#pragma unroll
      for (int c = 0; c < 3; ++c)
#pragma unroll
        for (int i = 0; i < 4; ++i)
          sm[c][i] += __shfl_xor(sm[c][i], off, 64);
    }
    if (tx == 0) {
#pragma unroll
      for (int c = 0; c < 3; ++c)
#pragma unroll
        for (int i = 0; i < 4; ++i) {
          int n = n0 + ty * 4 + i;
          rsum_g[((size_t)b * 3 + c) * NP + n] = sm[c][i];
        }
    }
  } else {
#pragma unroll
    for (int off = 1; off < 32; off <<= 1) {
#pragma unroll
      for (int c = 0; c < 3; ++c)
#pragma unroll
        for (int i = 0; i < 4; ++i) {
          float o0 = __shfl_xor(t0[c][i], off, 64);
          float o1 = __shfl_xor(t1[c][i], off, 64);
          float o2 = __shfl_xor(t2[c][i], off, 64);
          top3_ins(t0[c][i], t1[c][i], t2[c][i], o0);
          top3_ins(t0[c][i], t1[c][i], t2[c][i], o1);
          top3_ins(t0[c][i], t1[c][i], t2[c][i], o2);
        }
    }
    if (tx == 0) {
#pragma unroll
      for (int c = 0; c < 3; ++c)
#pragma unroll
        for (int i = 0; i < 4; ++i) {
          int n = n0 + ty * 4 + i;
          int pr = n >> 5, pc = n & 31;
          float v0 = t0[c][i], v1 = t1[c][i], v2 = t2[c][i];
          int ii0, jj0, ii1 = -1, jj1 = -1;
          if (c == 0)      { ii0 = 2 * pr;     jj0 = 2 * pc; }
          else if (c == 1) { ii0 = 2 * pr + 1; jj0 = 2 * pc + 1; }
          else             { ii0 = 2 * pr;     jj0 = 2 * pc + 1;
                             ii1 = 2 * pr + 1; jj1 = 2 * pc; }
          out[(((size_t)b * 3 + 0) * NH + ii0) * NW + jj0] = v0;
          out[(((size_t)b * 3 + 1) * NH + ii0) * NW + jj0] = v1;
          out[(((size_t)b * 3 + 2) * NH + ii0) * NW + jj0] = v2;
          if (ii1 >= 0) {
            out[(((size_t)b * 3 + 0) * NH + ii1) * NW + jj1] = v0;
            out[(((size_t)b * 3 + 1) * NH + ii1) * NW + jj1] = v1;
            out[(((size_t)b * 3 + 2) * NH + ii1) * NW + jj1] = v2;
          }
        }
    }
  }
}

extern "C" void kernel_launch(void* const* d_in, const int* in_sizes, int n_in,
                              void* d_out, int out_size, void* d_ws, size_t ws_size,
                              hipStream_t stream) {
  const float* x = (const float*)d_in[0];
  const float* alpha = (const float*)d_in[1];
  float* out = (float*)d_out;

  const size_t nVsU = (size_t)NB * 6 * NP * NCH;          // ushorts: 25.2 MB
  const size_t nRs = (size_t)NB * 3 * NP;                 // floats
  const size_t nSbuf = (size_t)NB * NTILE * 32 * TM;      // float2 slots: 75.5 MB
  const size_t nP = (size_t)NB * NTILE * 160 * 9;         // floats: 13.3 MB

  ushort* Vs = (ushort*)d_ws;
  float* rsum = (float*)(Vs + nVsU);
  float2* Sbuf = (float2*)(rsum + nRs);
  float* P = (float*)(Sbuf + nSbuf);

  const size_t need_bytes = nVsU * 2 + nRs * 4 + nSbuf * 8 + nP * 4;

  if (ws_size >= need_bytes) {
    prep_split<<<512, 256, 0, stream>>>(x, Vs, rsum);
    gemm_mfma<<<NTILE * NB, 256, 0, stream>>>(Vs, alpha, Sbuf, rsum);
    recip_kernel<<<(NB * 3 * NP + 255) / 256, 256, 0, stream>>>(rsum, NB * 3 * NP);
    tile_topk<<<dim3(NTILE, NB), 256, 0, stream>>>(Sbuf, rsum, P);
    merge_kernel<<<(NB * 3 * NP) / 256, 256, 0, stream>>>(P, out);
  } else {
    float* V = (float*)d_ws;
    float* rsum_f = V + (size_t)NB * 2 * NP * NCH;
    prep_kernel<<<128, 256, 0, stream>>>(x, V);
    corr_kernel<1><<<dim3(NP / TN, NB), 256, 0, stream>>>(V, alpha, rsum_f, out);
    corr_kernel<2><<<dim3(NP / TN, NB), 256, 0, stream>>>(V, alpha, rsum_f, out);
  }
}